// Round 4
// baseline (187.402 us; speedup 1.0000x reference)
//
#include <hip/hip_runtime.h>
#include <math.h>
#include <stdint.h>

#define BB 8
#define SS 2048
#define EE 1024
#define DKK 64

typedef _Float16 half8 __attribute__((ext_vector_type(8)));
typedef float floatx4 __attribute__((ext_vector_type(4)));

__device__ __forceinline__ void split8(float4 a, float4 b, half8& hi, half8& lo) {
  float va[8] = {a.x, a.y, a.z, a.w, b.x, b.y, b.z, b.w};
#pragma unroll
  for (int j = 0; j < 8; ++j) {
    _Float16 h = (_Float16)va[j];
    hi[j] = h;
    lo[j] = (_Float16)(va[j] - (float)h);
  }
}

// ---------------------------------------------------------------------------
// MFMA projection via split-fp16 (3-term), fp16 outputs.
// blockIdx.y = 0:Q, 1:K, 2:V(transposed out). Tile 64x64, BK=64, 4 waves.
// ---------------------------------------------------------------------------
__global__ __launch_bounds__(256, 3) void proj_kernel(
    const float* __restrict__ q_in, const float* __restrict__ k_in,
    const float* __restrict__ v_in,
    const float* __restrict__ w_q, const float* __restrict__ b_q,
    const float* __restrict__ w_k, const float* __restrict__ b_k,
    const float* __restrict__ w_v, const float* __restrict__ b_v,
    _Float16* __restrict__ Qh, _Float16* __restrict__ Kh,
    _Float16* __restrict__ VhT) {
  const int which = blockIdx.y;
  const float* X = which == 0 ? q_in : (which == 1 ? k_in : v_in);
  const float* W = which == 0 ? w_q : (which == 1 ? w_k : w_v);
  const float* bias = which == 0 ? b_q : (which == 1 ? b_k : b_v);

  __shared__ __align__(16) char Xh[64 * 128];
  __shared__ __align__(16) char Xl[64 * 128];
  __shared__ __align__(16) char Wh[64 * 128];
  __shared__ __align__(16) char Wl[64 * 128];

  const int t = threadIdx.x;
  const int row0 = blockIdx.x * 64;
  const int sr = t >> 2;
  const int c4 = t & 3;
  const int l = t & 63;
  const int li = l & 15, g = l >> 4;
  const int w = t >> 6;

  const float* xbase = X + (size_t)(row0 + sr) * EE + c4 * 16;
  const float* wbase = W + (size_t)sr * EE + c4 * 16;

  float4 xr[4], wr[4];
#pragma unroll
  for (int u = 0; u < 4; ++u) {
    xr[u] = ((const float4*)xbase)[u];
    wr[u] = ((const float4*)wbase)[u];
  }

  floatx4 acc[4];
#pragma unroll
  for (int c = 0; c < 4; ++c) acc[c] = (floatx4){0.f, 0.f, 0.f, 0.f};

  const int xrow_off = (w * 16 + li) * 128;
  const int swz = li & 7;

  for (int e0 = 0; e0 < EE; e0 += 64) {
    half8 xh0, xl0, xh1, xl1, wh0, wl0, wh1, wl1;
    split8(xr[0], xr[1], xh0, xl0);
    split8(xr[2], xr[3], xh1, xl1);
    split8(wr[0], wr[1], wh0, wl0);
    split8(wr[2], wr[3], wh1, wl1);
    __syncthreads();
    {
      const int p0 = ((c4 * 2 + 0) ^ (sr & 7)) * 16;
      const int p1 = ((c4 * 2 + 1) ^ (sr & 7)) * 16;
      *(half8*)(Xh + sr * 128 + p0) = xh0;
      *(half8*)(Xh + sr * 128 + p1) = xh1;
      *(half8*)(Xl + sr * 128 + p0) = xl0;
      *(half8*)(Xl + sr * 128 + p1) = xl1;
      *(half8*)(Wh + sr * 128 + p0) = wh0;
      *(half8*)(Wh + sr * 128 + p1) = wh1;
      *(half8*)(Wl + sr * 128 + p0) = wl0;
      *(half8*)(Wl + sr * 128 + p1) = wl1;
    }
    if (e0 + 64 < EE) {
#pragma unroll
      for (int u = 0; u < 4; ++u) {
        xr[u] = ((const float4*)(xbase + e0 + 64))[u];
        wr[u] = ((const float4*)(wbase + e0 + 64))[u];
      }
    }
    __syncthreads();
    half8 axh[2], axl[2];
#pragma unroll
    for (int h = 0; h < 2; ++h) {
      const int apos = ((h * 4 + g) ^ swz) * 16;
      axh[h] = *(const half8*)(Xh + xrow_off + apos);
      axl[h] = *(const half8*)(Xl + xrow_off + apos);
    }
#pragma unroll
    for (int c = 0; c < 4; ++c) {
      const int brow_off = (c * 16 + li) * 128;
#pragma unroll
      for (int h = 0; h < 2; ++h) {
        const int bpos = ((h * 4 + g) ^ swz) * 16;
        half8 bh = *(const half8*)(Wh + brow_off + bpos);
        half8 bl = *(const half8*)(Wl + brow_off + bpos);
        acc[c] = __builtin_amdgcn_mfma_f32_16x16x32_f16(axh[h], bh, acc[c], 0, 0, 0);
        acc[c] = __builtin_amdgcn_mfma_f32_16x16x32_f16(axh[h], bl, acc[c], 0, 0, 0);
        acc[c] = __builtin_amdgcn_mfma_f32_16x16x32_f16(axl[h], bh, acc[c], 0, 0, 0);
      }
    }
  }

  float bvv[4];
#pragma unroll
  for (int c = 0; c < 4; ++c) bvv[c] = bias[c * 16 + li];

  if (which < 2) {
    _Float16* P = (which == 0) ? Qh : Kh;
#pragma unroll
    for (int c = 0; c < 4; ++c)
#pragma unroll
      for (int r = 0; r < 4; ++r)
        P[(size_t)(row0 + w * 16 + g * 4 + r) * DKK + c * 16 + li] =
            (_Float16)(acc[c][r] + bvv[c]);
  } else {
    const int bb = row0 >> 11;
    const int s0 = row0 & (SS - 1);
#pragma unroll
    for (int c = 0; c < 4; ++c)
#pragma unroll
      for (int r = 0; r < 4; ++r)
        VhT[((size_t)bb * DKK + c * 16 + li) * SS + s0 + w * 16 + g * 4 + r] =
            (_Float16)(acc[c][r] + bvv[c]);
  }
}

// ---------------------------------------------------------------------------
// Flash kernel: single-pass swapped-QK attention. 512 thr, 32 q-rows, 8 waves
// (qh = w&1 selects 16 q-rows, ws = w>>1 selects a 32-wide k-stripe).
// Outputs: O (outsc), per-row (m, 1/l) to mstats, packed mask bits to mbits_g.
// Swapped MFMA: sc = mfma(A=K, B=Q) -> lane (g,li): q = li, k = stripe+cb*16+g*4+r.
// PV: O^T = mfma(A=V^T, B=P) with contraction-slot permutation
//   slot (g,j) <-> k = stripe + (j>>2)*16 + g*4 + (j&3), so P feeds B straight
//   from registers and V^T A-frags are two b64 LDS reads.
// ---------------------------------------------------------------------------
__global__ __launch_bounds__(512, 4) void flash_kernel(
    const _Float16* __restrict__ Qh, const _Float16* __restrict__ Kh,
    const _Float16* __restrict__ VhT, const int* __restrict__ mask,
    float* __restrict__ outsc, uint32_t* __restrict__ mbits_g,
    float* __restrict__ mstats) {
  __shared__ __align__(16) char Klds[16384];     // [128 k][64 d] f16, swz src
  __shared__ __align__(16) char Vlds[16384];     // [64 d][128 k] f16, swz src
  __shared__ uint32_t mwords[32][66];            // mask bits, padded
  __shared__ float Obuf[32][68];                 // combine buffer, padded
  __shared__ float mlbuf[8][16][2];              // per-wave (m, l)
  __shared__ float lstat[32][2];                 // per-q (m*, 1/l*)

  const int t = threadIdx.x;
  const int b = (int)blockIdx.x & 7;
  const int q0 = ((int)blockIdx.x >> 3) * 32;
  const int l = t & 63;
  const int li = l & 15, g = l >> 4;
  const int w = t >> 6;
  const int qh = w & 1, ws = w >> 1;
  const float SCALE = 0.125f;

  // ---- pack mask bits (coalesced read + ballot) ----
  {
    const int* mp = mask + ((size_t)b * SS + q0) * SS;
    for (int j = 0; j < 128; ++j) {
      const int flat = j * 512 + t;
      const int mz = (mp[flat] != 0);
      unsigned long long bal = __ballot(mz);
      if ((l & 31) == 0) {
        const uint32_t val = (uint32_t)(bal >> l);
        const int word = flat >> 5;
        const int qq = word >> 6, wc = word & 63;
        mwords[qq][wc] = val;
        mbits_g[((size_t)(b * SS + q0 + qq)) * 64 + wc] = val;
      }
    }
  }

  // Q B-fragments: lane (g,li): q = q0+qh*16+li, d-slots h*32+g*8..+7
  half8 aq[2];
  {
    const _Float16* qp = Qh + ((size_t)b * SS + q0 + qh * 16 + li) * DKK;
    aq[0] = *(const half8*)(qp + g * 8);
    aq[1] = *(const half8*)(qp + 32 + g * 8);
  }

  float m_c = -3.0e38f, l_c = 0.f;
  floatx4 O[4];
#pragma unroll
  for (int d = 0; d < 4; ++d) O[d] = (floatx4){0.f, 0.f, 0.f, 0.f};

  __syncthreads();  // mwords ready

  for (int kt = 0; kt < 16; ++kt) {
    // issue staging loads early (no LDS) -- overlap with previous compute
    half8 kv[2], vv[2];
#pragma unroll
    for (int p = 0; p < 2; ++p) {
      const int slot = t + p * 512;
      const int kr = slot >> 3, kc = slot & 7;
      kv[p] = *(const half8*)(Kh + ((size_t)b * SS + kt * 128 + kr) * DKK +
                              ((kc ^ (kr & 7)) * 8));
      const int vd = slot >> 4, vc = slot & 15;
      vv[p] = *(const half8*)(VhT + ((size_t)b * DKK + vd) * SS + kt * 128 +
                              ((vc ^ (vd & 7)) * 8));
    }
    __syncthreads();  // previous compute done with LDS
#pragma unroll
    for (int p = 0; p < 2; ++p) {
      const int slot = t + p * 512;
      *(half8*)(Klds + slot * 16) = kv[p];
      *(half8*)(Vlds + slot * 16) = vv[p];
    }
    __syncthreads();  // stage ready

    // QK^T (swapped): sc[cb][r] = S^T[k = ws*32+cb*16+g*4+r][q = li]
    floatx4 sc[2];
#pragma unroll
    for (int cb = 0; cb < 2; ++cb) {
      const int krow = ws * 32 + cb * 16 + li;
      const int rs = krow & 7;
      floatx4 acc = {0.f, 0.f, 0.f, 0.f};
#pragma unroll
      for (int h = 0; h < 2; ++h) {
        half8 ka = *(const half8*)(Klds + krow * 128 + (((h * 4 + g) ^ rs) * 16));
        acc = __builtin_amdgcn_mfma_f32_16x16x32_f16(ka, aq[h], acc, 0, 0, 0);
      }
      sc[cb] = acc;
    }

    // mask + online softmax (per-lane state, q = li)
    const uint32_t mw = mwords[qh * 16 + li][kt * 4 + ws];
    float p[2][4];
    float tmax = -3.0e38f;
#pragma unroll
    for (int cb = 0; cb < 2; ++cb)
#pragma unroll
      for (int r = 0; r < 4; ++r) {
        const float s =
            ((mw >> (cb * 16 + g * 4 + r)) & 1u) ? sc[cb][r] * SCALE : -1.0e9f;
        p[cb][r] = s;
        tmax = fmaxf(tmax, s);
      }
    tmax = fmaxf(tmax, __shfl_xor(tmax, 16));
    tmax = fmaxf(tmax, __shfl_xor(tmax, 32));
    const float m_new = fmaxf(m_c, tmax);
    const float alpha = __expf(m_c - m_new);
    m_c = m_new;
    float lsum = 0.f;
#pragma unroll
    for (int cb = 0; cb < 2; ++cb)
#pragma unroll
      for (int r = 0; r < 4; ++r) {
        p[cb][r] = __expf(p[cb][r] - m_new);
        lsum += p[cb][r];
      }
    l_c = l_c * alpha + lsum;

    // pack P as B-fragment: slot j<4 -> (cb=0, r=j), j>=4 -> (cb=1, r=j-4)
    half8 pB;
#pragma unroll
    for (int j = 0; j < 4; ++j) {
      pB[j] = (_Float16)p[0][j];
      pB[4 + j] = (_Float16)p[1][j];
    }

    // PV: O^T[d][q] accumulate; A = V^T slots (g,j) <-> k = ws*32+(j>>2)*16+g*4+(j&3)
#pragma unroll
    for (int dblk = 0; dblk < 4; ++dblk) {
      const int d = dblk * 16 + li;
      const int rowb = d * 256;
      const int c1 = ws * 4 + (g >> 1);
      const int c2 = c1 + 2;
      const int sub = (g & 1) * 8;
      uint2 a1 = *(const uint2*)(Vlds + rowb + ((c1 ^ (li & 7)) * 16) + sub);
      uint2 a2 = *(const uint2*)(Vlds + rowb + ((c2 ^ (li & 7)) * 16) + sub);
      half8 av;
      *(uint2*)&av = a1;
      *((uint2*)&av + 1) = a2;
      O[dblk] = O[dblk] * alpha;
      O[dblk] = __builtin_amdgcn_mfma_f32_16x16x32_f16(av, pB, O[dblk], 0, 0, 0);
    }
  }

  // ---- epilogue: combine across the 4 k-stripe waves ----
  l_c += __shfl_xor(l_c, 16);
  l_c += __shfl_xor(l_c, 32);
  if (g == 0) {
    mlbuf[w][li][0] = m_c;
    mlbuf[w][li][1] = l_c;
  }
  __syncthreads();
  float mstar = -3.0e38f;
#pragma unroll
  for (int p2 = 0; p2 < 4; ++p2)
    mstar = fmaxf(mstar, mlbuf[p2 * 2 + qh][li][0]);
  float lstar = 0.f;
#pragma unroll
  for (int p2 = 0; p2 < 4; ++p2)
    lstar += mlbuf[p2 * 2 + qh][li][1] * __expf(mlbuf[p2 * 2 + qh][li][0] - mstar);
  const float fown = __expf(m_c - mstar);
  if (g == 0 && ws == 0) {
    lstat[qh * 16 + li][0] = mstar;
    lstat[qh * 16 + li][1] = 1.f / lstar;
  }
#pragma unroll
  for (int dblk = 0; dblk < 4; ++dblk) O[dblk] = O[dblk] * fown;

  for (int ph = 0; ph < 4; ++ph) {
    if (ws == ph) {
      const int qq = qh * 16 + li;
#pragma unroll
      for (int dblk = 0; dblk < 4; ++dblk)
#pragma unroll
        for (int r = 0; r < 4; ++r) {
          const int d = dblk * 16 + g * 4 + r;
          if (ph == 0)
            Obuf[qq][d] = O[dblk][r];
          else
            Obuf[qq][d] += O[dblk][r];
        }
    }
    __syncthreads();
  }

  {
    const int qq = t >> 4;
    const int d0 = (t & 15) * 4;
    const float rl = lstat[qq][1];
    float4 o;
    o.x = Obuf[qq][d0 + 0] * rl;
    o.y = Obuf[qq][d0 + 1] * rl;
    o.z = Obuf[qq][d0 + 2] * rl;
    o.w = Obuf[qq][d0 + 3] * rl;
    *(float4*)(outsc + ((size_t)(b * SS + q0 + qq)) * DKK + d0) = o;
  }
  if (t < 32) {
    mstats[((size_t)(b * SS + q0 + t)) * 2 + 0] = lstat[t][0];
    mstats[((size_t)(b * SS + q0 + t)) * 2 + 1] = lstat[t][1];
  }
}

// ---------------------------------------------------------------------------
// Weights kernel: streaming GEMM + exp, natural layout, writes wts once.
// 512 thr, 32 q-rows, 8 waves (qh, cq: 32 k-cols each).
// ---------------------------------------------------------------------------
__global__ __launch_bounds__(512, 4) void weights_kernel(
    const _Float16* __restrict__ Qh, const _Float16* __restrict__ Kh,
    const uint32_t* __restrict__ mbits_g, const float* __restrict__ mstats,
    float* __restrict__ wts) {
  __shared__ __align__(16) char Klds[16384];

  const int t = threadIdx.x;
  const int b = (int)blockIdx.x & 7;
  const int q0 = ((int)blockIdx.x >> 3) * 32;
  const int l = t & 63;
  const int li = l & 15, g = l >> 4;
  const int w = t >> 6;
  const int qh = w & 1, cq = w >> 1;
  const float SCALE = 0.125f;

  half8 aq[2];
  {
    const _Float16* qp = Qh + ((size_t)b * SS + q0 + qh * 16 + li) * DKK;
    aq[0] = *(const half8*)(qp + g * 8);
    aq[1] = *(const half8*)(qp + 32 + g * 8);
  }
  float mr[4], rl[4];
#pragma unroll
  for (int r = 0; r < 4; ++r) {
    const size_t q = (size_t)b * SS + q0 + qh * 16 + g * 4 + r;
    mr[r] = mstats[q * 2 + 0];
    rl[r] = mstats[q * 2 + 1];
  }

  for (int kt = 0; kt < 16; ++kt) {
    half8 kv[2];
#pragma unroll
    for (int p = 0; p < 2; ++p) {
      const int slot = t + p * 512;
      const int kr = slot >> 3, kc = slot & 7;
      kv[p] = *(const half8*)(Kh + ((size_t)b * SS + kt * 128 + kr) * DKK +
                              ((kc ^ (kr & 7)) * 8));
    }
    uint32_t mw[4];
#pragma unroll
    for (int r = 0; r < 4; ++r)
      mw[r] = mbits_g[((size_t)(b * SS + q0 + qh * 16 + g * 4 + r)) * 64 +
                      kt * 4 + cq];
    __syncthreads();
#pragma unroll
    for (int p = 0; p < 2; ++p) {
      const int slot = t + p * 512;
      *(half8*)(Klds + slot * 16) = kv[p];
    }
    __syncthreads();
#pragma unroll
    for (int cb = 0; cb < 2; ++cb) {
      const int krow = cq * 32 + cb * 16 + li;
      const int rs = krow & 7;
      floatx4 acc = {0.f, 0.f, 0.f, 0.f};
#pragma unroll
      for (int h = 0; h < 2; ++h) {
        half8 kb = *(const half8*)(Klds + krow * 128 + (((h * 4 + g) ^ rs) * 16));
        acc = __builtin_amdgcn_mfma_f32_16x16x32_f16(aq[h], kb, acc, 0, 0, 0);
      }
#pragma unroll
      for (int r = 0; r < 4; ++r) {
        const float wv = ((mw[r] >> (cb * 16 + li)) & 1u)
                             ? __expf(acc[r] * SCALE - mr[r]) * rl[r]
                             : 0.f;
        wts[((size_t)(b * SS + q0 + qh * 16 + g * 4 + r)) * SS + kt * 128 +
            cq * 32 + cb * 16 + li] = wv;
      }
    }
  }
}

extern "C" void kernel_launch(void* const* d_in, const int* in_sizes, int n_in,
                              void* d_out, int out_size, void* d_ws, size_t ws_size,
                              hipStream_t stream) {
  (void)in_sizes; (void)n_in; (void)out_size; (void)ws_size;
  const float* k_in = (const float*)d_in[0];
  const float* q_in = (const float*)d_in[1];
  const float* v_in = (const float*)d_in[2];
  const int* mask = (const int*)d_in[3];
  const float* w_q = (const float*)d_in[4];
  const float* b_q = (const float*)d_in[5];
  const float* w_k = (const float*)d_in[6];
  const float* b_k = (const float*)d_in[7];
  const float* w_v = (const float*)d_in[8];
  const float* b_v = (const float*)d_in[9];

  float* out_scores = (float*)d_out;                        // [B,S,DK] f32
  float* out_weights = out_scores + (size_t)BB * SS * DKK;  // [B,S,S]  f32

  char* wsp = (char*)d_ws;
  const size_t nBSD = (size_t)BB * SS * DKK;
  _Float16* Qh = (_Float16*)wsp;                      // 2 MB
  _Float16* Kh = (_Float16*)(wsp + nBSD * 2);         // 2 MB
  _Float16* VhT = (_Float16*)(wsp + nBSD * 4);        // 2 MB
  uint32_t* mbits_g = (uint32_t*)(wsp + nBSD * 6);    // 4 MB
  float* mstats = (float*)(wsp + nBSD * 6 + (size_t)BB * SS * 64 * 4);

  proj_kernel<<<dim3(256, 3), 256, 0, stream>>>(q_in, k_in, v_in, w_q, b_q,
                                                w_k, b_k, w_v, b_v, Qh, Kh, VhT);
  flash_kernel<<<512, 512, 0, stream>>>(Qh, Kh, VhT, mask, out_scores,
                                        mbits_g, mstats);
  weights_kernel<<<512, 512, 0, stream>>>(Qh, Kh, mbits_g, mstats, out_weights);
}

// Round 5
// 184.180 us; speedup vs baseline: 1.0175x; 1.0175x over previous
//
#include <hip/hip_runtime.h>
#include <math.h>
#include <stdint.h>

#define BB 8
#define SS 2048
#define EE 1024
#define DKK 64

typedef _Float16 half8 __attribute__((ext_vector_type(8)));
typedef float floatx4 __attribute__((ext_vector_type(4)));

__device__ __forceinline__ void split8(float4 a, float4 b, half8& hi, half8& lo) {
  float va[8] = {a.x, a.y, a.z, a.w, b.x, b.y, b.z, b.w};
#pragma unroll
  for (int j = 0; j < 8; ++j) {
    _Float16 h = (_Float16)va[j];
    hi[j] = h;
    lo[j] = (_Float16)(va[j] - (float)h);
  }
}

// ---------------------------------------------------------------------------
// MFMA projection via split-fp16 (3-term), fp16 outputs. (unchanged)
// ---------------------------------------------------------------------------
__global__ __launch_bounds__(256, 3) void proj_kernel(
    const float* __restrict__ q_in, const float* __restrict__ k_in,
    const float* __restrict__ v_in,
    const float* __restrict__ w_q, const float* __restrict__ b_q,
    const float* __restrict__ w_k, const float* __restrict__ b_k,
    const float* __restrict__ w_v, const float* __restrict__ b_v,
    _Float16* __restrict__ Qh, _Float16* __restrict__ Kh,
    _Float16* __restrict__ VhT) {
  const int which = blockIdx.y;
  const float* X = which == 0 ? q_in : (which == 1 ? k_in : v_in);
  const float* W = which == 0 ? w_q : (which == 1 ? w_k : w_v);
  const float* bias = which == 0 ? b_q : (which == 1 ? b_k : b_v);

  __shared__ __align__(16) char Xh[64 * 128];
  __shared__ __align__(16) char Xl[64 * 128];
  __shared__ __align__(16) char Wh[64 * 128];
  __shared__ __align__(16) char Wl[64 * 128];

  const int t = threadIdx.x;
  const int row0 = blockIdx.x * 64;
  const int sr = t >> 2;
  const int c4 = t & 3;
  const int l = t & 63;
  const int li = l & 15, g = l >> 4;
  const int w = t >> 6;

  const float* xbase = X + (size_t)(row0 + sr) * EE + c4 * 16;
  const float* wbase = W + (size_t)sr * EE + c4 * 16;

  float4 xr[4], wr[4];
#pragma unroll
  for (int u = 0; u < 4; ++u) {
    xr[u] = ((const float4*)xbase)[u];
    wr[u] = ((const float4*)wbase)[u];
  }

  floatx4 acc[4];
#pragma unroll
  for (int c = 0; c < 4; ++c) acc[c] = (floatx4){0.f, 0.f, 0.f, 0.f};

  const int xrow_off = (w * 16 + li) * 128;
  const int swz = li & 7;

  for (int e0 = 0; e0 < EE; e0 += 64) {
    half8 xh0, xl0, xh1, xl1, wh0, wl0, wh1, wl1;
    split8(xr[0], xr[1], xh0, xl0);
    split8(xr[2], xr[3], xh1, xl1);
    split8(wr[0], wr[1], wh0, wl0);
    split8(wr[2], wr[3], wh1, wl1);
    __syncthreads();
    {
      const int p0 = ((c4 * 2 + 0) ^ (sr & 7)) * 16;
      const int p1 = ((c4 * 2 + 1) ^ (sr & 7)) * 16;
      *(half8*)(Xh + sr * 128 + p0) = xh0;
      *(half8*)(Xh + sr * 128 + p1) = xh1;
      *(half8*)(Xl + sr * 128 + p0) = xl0;
      *(half8*)(Xl + sr * 128 + p1) = xl1;
      *(half8*)(Wh + sr * 128 + p0) = wh0;
      *(half8*)(Wh + sr * 128 + p1) = wh1;
      *(half8*)(Wl + sr * 128 + p0) = wl0;
      *(half8*)(Wl + sr * 128 + p1) = wl1;
    }
    if (e0 + 64 < EE) {
#pragma unroll
      for (int u = 0; u < 4; ++u) {
        xr[u] = ((const float4*)(xbase + e0 + 64))[u];
        wr[u] = ((const float4*)(wbase + e0 + 64))[u];
      }
    }
    __syncthreads();
    half8 axh[2], axl[2];
#pragma unroll
    for (int h = 0; h < 2; ++h) {
      const int apos = ((h * 4 + g) ^ swz) * 16;
      axh[h] = *(const half8*)(Xh + xrow_off + apos);
      axl[h] = *(const half8*)(Xl + xrow_off + apos);
    }
#pragma unroll
    for (int c = 0; c < 4; ++c) {
      const int brow_off = (c * 16 + li) * 128;
#pragma unroll
      for (int h = 0; h < 2; ++h) {
        const int bpos = ((h * 4 + g) ^ swz) * 16;
        half8 bh = *(const half8*)(Wh + brow_off + bpos);
        half8 bl = *(const half8*)(Wl + brow_off + bpos);
        acc[c] = __builtin_amdgcn_mfma_f32_16x16x32_f16(axh[h], bh, acc[c], 0, 0, 0);
        acc[c] = __builtin_amdgcn_mfma_f32_16x16x32_f16(axh[h], bl, acc[c], 0, 0, 0);
        acc[c] = __builtin_amdgcn_mfma_f32_16x16x32_f16(axl[h], bh, acc[c], 0, 0, 0);
      }
    }
  }

  float bvv[4];
#pragma unroll
  for (int c = 0; c < 4; ++c) bvv[c] = bias[c * 16 + li];

  if (which < 2) {
    _Float16* P = (which == 0) ? Qh : Kh;
#pragma unroll
    for (int c = 0; c < 4; ++c)
#pragma unroll
      for (int r = 0; r < 4; ++r)
        P[(size_t)(row0 + w * 16 + g * 4 + r) * DKK + c * 16 + li] =
            (_Float16)(acc[c][r] + bvv[c]);
  } else {
    const int bb = row0 >> 11;
    const int s0 = row0 & (SS - 1);
#pragma unroll
    for (int c = 0; c < 4; ++c)
#pragma unroll
      for (int r = 0; r < 4; ++r)
        VhT[((size_t)bb * DKK + c * 16 + li) * SS + s0 + w * 16 + g * 4 + r] =
            (_Float16)(acc[c][r] + bvv[c]);
  }
}

// ---------------------------------------------------------------------------
// Flash kernel: single-pass swapped-QK attention. 512 thr, 32 q-rows, 8 waves.
// K fragments read DIRECT from L2-hot Kh (no LDS); V staged in LDS with
// one-tile-ahead register prefetch; mask packed via per-thread int4 loads.
// ---------------------------------------------------------------------------
__global__ __launch_bounds__(512, 4) void flash_kernel(
    const _Float16* __restrict__ Qh, const _Float16* __restrict__ Kh,
    const _Float16* __restrict__ VhT, const int* __restrict__ mask,
    float* __restrict__ outsc, uint32_t* __restrict__ mbits_g,
    float* __restrict__ mstats) {
  __shared__ __align__(16) char Vlds[16384];  // [64 d][128 k] f16, swz src
  __shared__ uint32_t mwords[32][66];         // mask bits, padded
  __shared__ float Obuf[32][68];              // combine buffer, padded
  __shared__ float mlbuf[8][16][2];           // per-wave (m, l)
  __shared__ float lstat[32][2];              // per-q (m*, 1/l*)

  const int t = threadIdx.x;
  const int b = (int)blockIdx.x & 7;
  const int q0 = ((int)blockIdx.x >> 3) * 32;
  const int l = t & 63;
  const int li = l & 15, g = l >> 4;
  const int w = t >> 6;
  const int qh = w & 1, ws = w >> 1;
  const float SCALE = 0.125f;

  // ---- pack mask: thread t packs words [t*4, t*4+4) (32 ints each) ----
  {
    const int* mp = mask + ((size_t)b * SS + q0) * SS;
    uint32_t wbuf[4];
#pragma unroll
    for (int u = 0; u < 4; ++u) {
      const int word = t * 4 + u;
      const int4* src = (const int4*)(mp + word * 32);
      uint32_t bits = 0;
#pragma unroll
      for (int c = 0; c < 8; ++c) {
        int4 m4 = src[c];
        bits |= (uint32_t)(m4.x != 0) << (c * 4 + 0);
        bits |= (uint32_t)(m4.y != 0) << (c * 4 + 1);
        bits |= (uint32_t)(m4.z != 0) << (c * 4 + 2);
        bits |= (uint32_t)(m4.w != 0) << (c * 4 + 3);
      }
      wbuf[u] = bits;
      mwords[word >> 6][word & 63] = bits;
    }
    *(uint4*)(mbits_g + ((size_t)(b * SS + q0)) * 64 + t * 4) =
        *(const uint4*)wbuf;
  }

  // Q B-fragments: lane (g,li): q = q0+qh*16+li, d-slots h*32+g*8..+7
  half8 aq[2];
  {
    const _Float16* qp = Qh + ((size_t)b * SS + q0 + qh * 16 + li) * DKK;
    aq[0] = *(const half8*)(qp + g * 8);
    aq[1] = *(const half8*)(qp + 32 + g * 8);
  }

  float m_c = -3.0e38f, l_c = 0.f;
  floatx4 O[4];
#pragma unroll
  for (int d = 0; d < 4; ++d) O[d] = (floatx4){0.f, 0.f, 0.f, 0.f};

  // V prefetch for tile 0
  half8 vv[2];
#pragma unroll
  for (int p = 0; p < 2; ++p) {
    const int slot = t + p * 512;
    const int vd = slot >> 4, vc = slot & 15;
    vv[p] = *(const half8*)(VhT + ((size_t)b * DKK + vd) * SS +
                            ((vc ^ (vd & 7)) * 8));
  }

  const _Float16* kbase = Kh + (size_t)b * SS * DKK;

  for (int kt = 0; kt < 16; ++kt) {
    __syncthreads();  // prev PV done reading Vlds; (kt=0: mwords ready)
#pragma unroll
    for (int p = 0; p < 2; ++p)
      *(half8*)(Vlds + (t + p * 512) * 16) = vv[p];
    __syncthreads();
    if (kt + 1 < 16) {  // prefetch next V tile; hides under compute
#pragma unroll
      for (int p = 0; p < 2; ++p) {
        const int slot = t + p * 512;
        const int vd = slot >> 4, vc = slot & 15;
        vv[p] = *(const half8*)(VhT + ((size_t)b * DKK + vd) * SS +
                                (kt + 1) * 128 + ((vc ^ (vd & 7)) * 8));
      }
    }

    // QK^T (swapped): sc[cb][r] = S^T[k = ws*32+cb*16+g*4+r][q = li]
    half8 ka[2][2];
#pragma unroll
    for (int cb = 0; cb < 2; ++cb) {
      const int krow = ws * 32 + cb * 16 + li;
      const _Float16* kp = kbase + (size_t)(kt * 128 + krow) * DKK;
      ka[cb][0] = *(const half8*)(kp + g * 8);
      ka[cb][1] = *(const half8*)(kp + 32 + g * 8);
    }
    floatx4 sc[2];
#pragma unroll
    for (int cb = 0; cb < 2; ++cb) {
      floatx4 acc = {0.f, 0.f, 0.f, 0.f};
      acc = __builtin_amdgcn_mfma_f32_16x16x32_f16(ka[cb][0], aq[0], acc, 0, 0, 0);
      acc = __builtin_amdgcn_mfma_f32_16x16x32_f16(ka[cb][1], aq[1], acc, 0, 0, 0);
      sc[cb] = acc;
    }

    // mask + online softmax (per-lane state, q = li)
    const uint32_t mw = mwords[qh * 16 + li][kt * 4 + ws];
    float p[2][4];
    float tmax = -3.0e38f;
#pragma unroll
    for (int cb = 0; cb < 2; ++cb)
#pragma unroll
      for (int r = 0; r < 4; ++r) {
        const float s =
            ((mw >> (cb * 16 + g * 4 + r)) & 1u) ? sc[cb][r] * SCALE : -1.0e9f;
        p[cb][r] = s;
        tmax = fmaxf(tmax, s);
      }
    tmax = fmaxf(tmax, __shfl_xor(tmax, 16));
    tmax = fmaxf(tmax, __shfl_xor(tmax, 32));
    const float m_new = fmaxf(m_c, tmax);
    const float alpha = __expf(m_c - m_new);
    m_c = m_new;
    float lsum = 0.f;
#pragma unroll
    for (int cb = 0; cb < 2; ++cb)
#pragma unroll
      for (int r = 0; r < 4; ++r) {
        p[cb][r] = __expf(p[cb][r] - m_new);
        lsum += p[cb][r];
      }
    l_c = l_c * alpha + lsum;

    // pack P as B-fragment: slot j<4 -> (cb=0, r=j), j>=4 -> (cb=1, r=j-4)
    half8 pB;
#pragma unroll
    for (int j = 0; j < 4; ++j) {
      pB[j] = (_Float16)p[0][j];
      pB[4 + j] = (_Float16)p[1][j];
    }

    // PV: O^T[d][q]; A = V^T slots (g,j) <-> k = ws*32+(j>>2)*16+g*4+(j&3)
#pragma unroll
    for (int dblk = 0; dblk < 4; ++dblk) {
      const int d = dblk * 16 + li;
      const int rowb = d * 256;
      const int c1 = ws * 4 + (g >> 1);
      const int c2 = c1 + 2;
      const int sub = (g & 1) * 8;
      uint2 a1 = *(const uint2*)(Vlds + rowb + ((c1 ^ (li & 7)) * 16) + sub);
      uint2 a2 = *(const uint2*)(Vlds + rowb + ((c2 ^ (li & 7)) * 16) + sub);
      half8 av;
      *(uint2*)&av = a1;
      *((uint2*)&av + 1) = a2;
      O[dblk] = O[dblk] * alpha;
      O[dblk] = __builtin_amdgcn_mfma_f32_16x16x32_f16(av, pB, O[dblk], 0, 0, 0);
    }
  }

  // ---- epilogue: combine across the 4 k-stripe waves ----
  l_c += __shfl_xor(l_c, 16);
  l_c += __shfl_xor(l_c, 32);
  if (g == 0) {
    mlbuf[w][li][0] = m_c;
    mlbuf[w][li][1] = l_c;
  }
  __syncthreads();
  float mstar = -3.0e38f;
#pragma unroll
  for (int p2 = 0; p2 < 4; ++p2)
    mstar = fmaxf(mstar, mlbuf[p2 * 2 + qh][li][0]);
  float lstar = 0.f;
#pragma unroll
  for (int p2 = 0; p2 < 4; ++p2)
    lstar += mlbuf[p2 * 2 + qh][li][1] * __expf(mlbuf[p2 * 2 + qh][li][0] - mstar);
  const float fown = __expf(m_c - mstar);
  if (g == 0 && ws == 0) {
    lstat[qh * 16 + li][0] = mstar;
    lstat[qh * 16 + li][1] = 1.f / lstar;
  }
#pragma unroll
  for (int dblk = 0; dblk < 4; ++dblk) O[dblk] = O[dblk] * fown;

  for (int ph = 0; ph < 4; ++ph) {
    if (ws == ph) {
      const int qq = qh * 16 + li;
#pragma unroll
      for (int dblk = 0; dblk < 4; ++dblk)
#pragma unroll
        for (int r = 0; r < 4; ++r) {
          const int d = dblk * 16 + g * 4 + r;
          if (ph == 0)
            Obuf[qq][d] = O[dblk][r];
          else
            Obuf[qq][d] += O[dblk][r];
        }
    }
    __syncthreads();
  }

  {
    const int qq = t >> 4;
    const int d0 = (t & 15) * 4;
    const float rl = lstat[qq][1];
    float4 o;
    o.x = Obuf[qq][d0 + 0] * rl;
    o.y = Obuf[qq][d0 + 1] * rl;
    o.z = Obuf[qq][d0 + 2] * rl;
    o.w = Obuf[qq][d0 + 3] * rl;
    *(float4*)(outsc + ((size_t)(b * SS + q0 + qq)) * DKK + d0) = o;
  }
  if (t < 32) {
    mstats[((size_t)(b * SS + q0 + t)) * 2 + 0] = lstat[t][0];
    mstats[((size_t)(b * SS + q0 + t)) * 2 + 1] = lstat[t][1];
  }
}

// ---------------------------------------------------------------------------
// Weights kernel: streaming GEMM + exp, no LDS, no barriers. K direct from L2.
// 512 thr, 32 q-rows, 8 waves (qh, cq: 32 k-cols each).
// ---------------------------------------------------------------------------
__global__ __launch_bounds__(512) void weights_kernel(
    const _Float16* __restrict__ Qh, const _Float16* __restrict__ Kh,
    const uint32_t* __restrict__ mbits_g, const float* __restrict__ mstats,
    float* __restrict__ wts) {
  const int t = threadIdx.x;
  const int b = (int)blockIdx.x & 7;
  const int q0 = ((int)blockIdx.x >> 3) * 32;
  const int l = t & 63;
  const int li = l & 15, g = l >> 4;
  const int w = t >> 6;
  const int qh = w & 1, cq = w >> 1;
  const float SCALE = 0.125f;

  half8 aq[2];
  {
    const _Float16* qp = Qh + ((size_t)b * SS + q0 + qh * 16 + li) * DKK;
    aq[0] = *(const half8*)(qp + g * 8);
    aq[1] = *(const half8*)(qp + 32 + g * 8);
  }
  float mr[4], rl[4];
#pragma unroll
  for (int r = 0; r < 4; ++r) {
    const size_t q = (size_t)b * SS + q0 + qh * 16 + g * 4 + r;
    mr[r] = mstats[q * 2 + 0];
    rl[r] = mstats[q * 2 + 1];
  }
  const _Float16* kbase = Kh + (size_t)b * SS * DKK;

  for (int kt = 0; kt < 16; ++kt) {
    uint32_t mw[4];
#pragma unroll
    for (int r = 0; r < 4; ++r)
      mw[r] = mbits_g[((size_t)(b * SS + q0 + qh * 16 + g * 4 + r)) * 64 +
                      kt * 4 + cq];
    half8 kb[2][2];
#pragma unroll
    for (int cb = 0; cb < 2; ++cb) {
      const int krow = cq * 32 + cb * 16 + li;
      const _Float16* kp = kbase + (size_t)(kt * 128 + krow) * DKK;
      kb[cb][0] = *(const half8*)(kp + g * 8);
      kb[cb][1] = *(const half8*)(kp + 32 + g * 8);
    }
#pragma unroll
    for (int cb = 0; cb < 2; ++cb) {
      floatx4 acc = {0.f, 0.f, 0.f, 0.f};
      acc = __builtin_amdgcn_mfma_f32_16x16x32_f16(aq[0], kb[cb][0], acc, 0, 0, 0);
      acc = __builtin_amdgcn_mfma_f32_16x16x32_f16(aq[1], kb[cb][1], acc, 0, 0, 0);
#pragma unroll
      for (int r = 0; r < 4; ++r) {
        const float wv = ((mw[r] >> (cb * 16 + li)) & 1u)
                             ? __expf(acc[r] * SCALE - mr[r]) * rl[r]
                             : 0.f;
        wts[((size_t)(b * SS + q0 + qh * 16 + g * 4 + r)) * SS + kt * 128 +
            cq * 32 + cb * 16 + li] = wv;
      }
    }
  }
}

extern "C" void kernel_launch(void* const* d_in, const int* in_sizes, int n_in,
                              void* d_out, int out_size, void* d_ws, size_t ws_size,
                              hipStream_t stream) {
  (void)in_sizes; (void)n_in; (void)out_size; (void)ws_size;
  const float* k_in = (const float*)d_in[0];
  const float* q_in = (const float*)d_in[1];
  const float* v_in = (const float*)d_in[2];
  const int* mask = (const int*)d_in[3];
  const float* w_q = (const float*)d_in[4];
  const float* b_q = (const float*)d_in[5];
  const float* w_k = (const float*)d_in[6];
  const float* b_k = (const float*)d_in[7];
  const float* w_v = (const float*)d_in[8];
  const float* b_v = (const float*)d_in[9];

  float* out_scores = (float*)d_out;                        // [B,S,DK] f32
  float* out_weights = out_scores + (size_t)BB * SS * DKK;  // [B,S,S]  f32

  char* wsp = (char*)d_ws;
  const size_t nBSD = (size_t)BB * SS * DKK;
  _Float16* Qh = (_Float16*)wsp;                      // 2 MB
  _Float16* Kh = (_Float16*)(wsp + nBSD * 2);         // 2 MB
  _Float16* VhT = (_Float16*)(wsp + nBSD * 4);        // 2 MB
  uint32_t* mbits_g = (uint32_t*)(wsp + nBSD * 6);    // 4 MB
  float* mstats = (float*)(wsp + nBSD * 6 + (size_t)BB * SS * 64 * 4);

  proj_kernel<<<dim3(256, 3), 256, 0, stream>>>(q_in, k_in, v_in, w_q, b_q,
                                                w_k, b_k, w_v, b_v, Qh, Kh, VhT);
  flash_kernel<<<512, 512, 0, stream>>>(Qh, Kh, VhT, mask, out_scores,
                                        mbits_g, mstats);
  weights_kernel<<<512, 512, 0, stream>>>(Qh, Kh, mbits_g, mstats, out_weights);
}